// Round 13
// baseline (2916.540 us; speedup 1.0000x reference)
//
#include <hip/hip_runtime.h>
#include <hip/hip_fp16.h>

#define SEQT 2048
#define HID  256
#define NB   64

typedef int int32x4 __attribute__((ext_vector_type(4)));
typedef _Float16 h2 __attribute__((ext_vector_type(2)));

#define LOG2E 1.4426950408889634f
static __device__ __forceinline__ float sigf(float x) {
  return __builtin_amdgcn_rcpf(1.f + __builtin_amdgcn_exp2f(-LOG2E * x));
}
static __device__ __forceinline__ float tanhf_fast(float x) {
  float e = __builtin_amdgcn_exp2f(-2.f * LOG2E * fabsf(x));
  float r = (1.f - e) * __builtin_amdgcn_rcpf(1.f + e);
  return copysignf(r, x);
}
static __device__ __forceinline__ float max4(float4 f) {
  return fmaxf(fmaxf(fabsf(f.x), fabsf(f.y)), fmaxf(fabsf(f.z), fabsf(f.w)));
}

// One WG (512 thr = 8 waves) per BATCH PAIR (32 WGs). Whh is batch-invariant,
// so the AGPR-resident i8 A-fragments (128 dw/thread) serve two batches free.
// Phase-interleaved recurrence hides R12's ~900cyc serial tail (act chain +
// ds latency + barrier) under the other batch's 32-MFMA issue stream:
//   phase1: act(B,s-1) [+bf0 ds_read hides under it] ; MFMA(A,s) ; barrier
//   phase3: act(A,s)   [+bf1 ds_read]                ; MFMA(B,s) ; barrier
// acc liveness: accA (phase1->phase3) + accB (phase3->next phase1) = 64 dw;
// total reg demand ~244 < 256/wave budget at 2 waves/SIMD.
// Row/lane mapping identical to R12 (HW-validated): wave w owns all 4 gates of
// units [32w,32w+32); tile r=(q,sh) rows q*256+32w+16sh+lm; lane (ko,lm) reg j
// = row 4ko+j; unit u=32w+16su+4ko+ru; gate q of u = acc[2q+su][ru].
// Per-row weight scales; i8 h rings (16 slots) per batch; f16 rings flushed to
// hist every 16 steps (vmcnt drain amortized).
__global__ __attribute__((amdgpu_flat_work_group_size(512, 512),
                          amdgpu_waves_per_eu(2, 2)))
void lstm_main(const float* __restrict__ x, const float* __restrict__ Wih,
               const float* __restrict__ Whh, const float* __restrict__ bih,
               const float* __restrict__ bhh, float* __restrict__ out,
               unsigned* __restrict__ hist)   // hist f16x2 dwords: [b][step][128]
{
  __shared__ __align__(16) unsigned char qring0[16 * 256];  // i8 h ring, batch A
  __shared__ __align__(16) unsigned char qring1[16 * 256];  // i8 h ring, batch B
  __shared__ __align__(16) unsigned      f16r0[16 * 128];   // f16 h ring, batch A
  __shared__ __align__(16) unsigned      f16r1[16 * 128];   // f16 h ring, batch B
  __shared__ float xs0[SEQT], xs1[SEQT];
  __shared__ float rowS[1024];                              // per-row gate scale

  const int t    = threadIdx.x;
  const int bA   = 2 * blockIdx.x;
  const int bB   = bA + 1;
  const int w    = t >> 6;
  const int lane = t & 63;
  const int ko   = lane >> 4;       // k-16-group / D-row-quad 0..3
  const int lm   = lane & 15;       // A-row within tile / D-col
  const int su   = (lm >> 2) & 1;   // tile-half this lane activates
  const int ru   = lm & 3;          // reg this lane activates
  const int u    = 32 * w + 16 * su + 4 * ko + ru;   // unit (dup for lm>=8)

  ((float4*)xs0)[t] = ((const float4*)(x + (size_t)bA * SEQT))[t];
  ((float4*)xs1)[t] = ((const float4*)(x + (size_t)bB * SEQT))[t];
  if (t < 64) {                                      // zero slot 15 (h pre-step0)
    ((unsigned*)qring0)[15 * 64 + t] = 0u;
    ((unsigned*)qring1)[15 * 64 + t] = 0u;
  }

  // ---- per-row max + quantize A-fragments (128 dw/thread -> AGPR) ----
  int32x4 af[8][4];
#pragma unroll
  for (int r = 0; r < 8; ++r) {
    const int q = r >> 1, sh = r & 1;
    const int row = q * 256 + 32 * w + 16 * sh + lm;
    const float* rp = Whh + (size_t)row * HID + 16 * ko;
    float mx = 1e-20f;
#pragma unroll
    for (int kt = 0; kt < 4; ++kt) {
      const float4* p = (const float4*)(rp + 64 * kt);
      mx = fmaxf(mx, fmaxf(fmaxf(max4(p[0]), max4(p[1])),
                           fmaxf(max4(p[2]), max4(p[3]))));
    }
    mx = fmaxf(mx, __shfl_xor(mx, 16, 64));   // reduce across ko groups
    mx = fmaxf(mx, __shfl_xor(mx, 32, 64));
    const float winv = 127.f / mx;
    if (ko == 0) rowS[row] = mx * (1.f / (127.f * 127.f));
#pragma unroll
    for (int kt = 0; kt < 4; ++kt) {
      const float4* p = (const float4*)(rp + 64 * kt);
      int32x4 v;
#pragma unroll
      for (int d = 0; d < 4; ++d) {
        float4 f = p[d];
        int q0 = (int)__builtin_rintf(f.x * winv);
        int q1 = (int)__builtin_rintf(f.y * winv);
        int q2 = (int)__builtin_rintf(f.z * winv);
        int q3 = (int)__builtin_rintf(f.w * winv);
        v[d] = (q0 & 255) | ((q1 & 255) << 8) | ((q2 & 255) << 16) | ((q3 & 255) << 24);
      }
      af[r][kt] = v;
    }
  }

  float biasu[4], wihu[4];
#pragma unroll
  for (int q = 0; q < 4; ++q) {
    int row = q * 256 + u;
    biasu[q] = bih[row] + bhh[row];
    wihu[q]  = Wih[row];
  }
  __syncthreads();
  float Su[4];
#pragma unroll
  for (int q = 0; q < 4; ++q) Su[q] = rowS[q * 256 + u];

  unsigned* histb0 = hist + (size_t)bA * SEQT * 128;
  unsigned* histb1 = hist + (size_t)bB * SEQT * 128;
  float cA = 0.f, hA = 0.f, cB = 0.f, hB = 0.f;
  const int32x4 z4 = {0, 0, 0, 0};
  int32x4 accA[8], accB[8];

  auto mfma_phase = [&](const unsigned char* qs, int32x4* acc) {
    int32x4 bf[4];
#pragma unroll
    for (int kt = 0; kt < 4; ++kt)
      bf[kt] = *(const int32x4*)(qs + 64 * kt + 16 * ko);
#pragma unroll
    for (int r = 0; r < 8; ++r)
      acc[r] = __builtin_amdgcn_mfma_i32_16x16x64_i8(af[r][0], bf[0], z4, 0, 0, 0);
#pragma unroll
    for (int kt = 1; kt < 4; ++kt)
#pragma unroll
      for (int r = 0; r < 8; ++r)
        acc[r] = __builtin_amdgcn_mfma_i32_16x16x64_i8(af[r][kt], bf[kt], acc[r], 0, 0, 0);
  };
  auto act_phase = [&](int32x4* acc, float xv, float& c, float& h) {
    float aq[4];
#pragma unroll
    for (int q = 0; q < 4; ++q) {
      int32x4 v0 = acc[2 * q], v1 = acc[2 * q + 1];
      int e0 = su ? v1[0] : v0[0];
      int e1 = su ? v1[1] : v0[1];
      int e2 = su ? v1[2] : v0[2];
      int e3 = su ? v1[3] : v0[3];
      int g01 = (ru & 1) ? e1 : e0;
      int g23 = (ru & 1) ? e3 : e2;
      int gv  = (ru & 2) ? g23 : g01;
      aq[q] = __builtin_fmaf((float)gv, Su[q],
                             __builtin_fmaf(wihu[q], xv, biasu[q]));
    }
    float I = sigf(aq[0]), F = sigf(aq[1]), G = tanhf_fast(aq[2]), O = sigf(aq[3]);
    c = F * c + I * G;
    h = O * tanhf_fast(c);
  };

  for (int s = 0; s < SEQT; ++s) {
    // ---- phase 1: act(B, s-1) (hides bf0 ds latency) ; MFMA(A, s) ----
    const unsigned char* qs0 = qring0 + ((s + 15) & 15) * 256;
    if (s) {
      act_phase(accB, xs1[s - 1], cB, hB);
      if (lm < 8) {
        int qv = (int)__builtin_rintf(hB * 127.f);
        qring1[((s - 1) & 15) * 256 + u]           = (char)qv;
        ((_Float16*)f16r1)[((s - 1) & 15) * 256 + u] = (_Float16)hB;
      }
    }
    mfma_phase(qs0, accA);
    __syncthreads();

    if ((s & 15) == 0 && s) {     // flush B-steps s-16..s-1
      uint4 v = *(const uint4*)(f16r1 + 4 * t);
      *(uint4*)(histb1 + (size_t)(s - 16) * 128 + 4 * t) = v;
    }

    // ---- phase 3: act(A, s) (hides bf1 ds latency) ; MFMA(B, s) ----
    const unsigned char* qs1 = qring1 + ((s + 15) & 15) * 256;
    act_phase(accA, xs0[s], cA, hA);
    if (lm < 8) {
      int qv = (int)__builtin_rintf(hA * 127.f);
      qring0[(s & 15) * 256 + u]           = (char)qv;
      ((_Float16*)f16r0)[(s & 15) * 256 + u] = (_Float16)hA;
    }
    mfma_phase(qs1, accB);
    __syncthreads();

    if ((s & 15) == 15) {         // flush A-steps s-15..s
      uint4 v = *(const uint4*)(f16r0 + 4 * t);
      *(uint4*)(histb0 + (size_t)(s - 15) * 128 + 4 * t) = v;
    }
  }

  // ---- epilogue: B's last step ----
  act_phase(accB, xs1[SEQT - 1], cB, hB);
  if (lm < 8)
    ((_Float16*)f16r1)[15 * 256 + u] = (_Float16)hB;
  __syncthreads();
  {
    uint4 v = *(const uint4*)(f16r1 + 4 * t);
    *(uint4*)(histb1 + (size_t)(SEQT - 16) * 128 + 4 * t) = v;
  }

  if (lm < 8) {
    out[NB * SEQT + bA * HID + u]            = hA;  // h_n
    out[NB * SEQT + bB * HID + u]            = hB;
    out[NB * SEQT + NB * HID + bA * HID + u] = cA;  // c_n
    out[NB * SEQT + NB * HID + bB * HID + u] = cB;
  }
}

// y[b,t] = Wfc . h[b,t,:] + bfc  — one wave per output, coalesced 8B/lane loads.
__global__ __launch_bounds__(256) void lstm_head(
    const unsigned* __restrict__ hist, const float* __restrict__ Wfc,
    const float* __restrict__ bfc, float* __restrict__ y)
{
  int gw   = (blockIdx.x * 256 + threadIdx.x) >> 6;  // global wave id = output idx
  int lane = threadIdx.x & 63;
  uint2 hv = ((const uint2*)(hist + (size_t)gw * 128))[lane];
  float4 w = ((const float4*)Wfc)[lane];
  h2 p0 = __builtin_bit_cast(h2, hv.x);
  h2 p1 = __builtin_bit_cast(h2, hv.y);
  float s = (float)p0.x * w.x + (float)p0.y * w.y +
            (float)p1.x * w.z + (float)p1.y * w.w;
#pragma unroll
  for (int m = 32; m; m >>= 1) s += __shfl_xor(s, m, 64);
  if (lane == 0) y[gw] = s + bfc[0];
}

extern "C" void kernel_launch(void* const* d_in, const int* in_sizes, int n_in,
                              void* d_out, int out_size, void* d_ws, size_t ws_size,
                              hipStream_t stream)
{
  const float* x   = (const float*)d_in[0];
  const float* Wih = (const float*)d_in[1];
  const float* Whh = (const float*)d_in[2];
  const float* bih = (const float*)d_in[3];
  const float* bhh = (const float*)d_in[4];
  const float* Wfc = (const float*)d_in[5];
  const float* bfc = (const float*)d_in[6];
  float* out      = (float*)d_out;
  unsigned* hist  = (unsigned*)d_ws;   // 64*2048*128 dwords = 64 MiB

  (void)in_sizes; (void)n_in; (void)out_size; (void)ws_size;

  lstm_main<<<dim3(NB / 2), dim3(512), 0, stream>>>(x, Wih, Whh, bih, bhh, out, hist);
  lstm_head<<<dim3((NB * SEQT) / 4), dim3(256), 0, stream>>>(hist, Wfc, bfc, out);
}

// Round 14
// 1779.700 us; speedup vs baseline: 1.6388x; 1.6388x over previous
//
#include <hip/hip_runtime.h>
#include <hip/hip_fp16.h>

#define SEQT 2048
#define HID  256
#define NB   64

typedef int int32x4 __attribute__((ext_vector_type(4)));
typedef _Float16 h2 __attribute__((ext_vector_type(2)));

#define LOG2E 1.4426950408889634f
static __device__ __forceinline__ float sigf(float x) {
  return __builtin_amdgcn_rcpf(1.f + __builtin_amdgcn_exp2f(-LOG2E * x));
}
static __device__ __forceinline__ float tanhf_fast(float x) {
  float e = __builtin_amdgcn_exp2f(-2.f * LOG2E * fabsf(x));
  float r = (1.f - e) * __builtin_amdgcn_rcpf(1.f + e);
  return copysignf(r, x);
}
static __device__ __forceinline__ float max4(float4 f) {
  return fmaxf(fmaxf(fabsf(f.x), fabsf(f.y)), fmaxf(fabsf(f.z), fabsf(f.w)));
}

// One WG per batch (64 WGs = 64 CUs), but 1024 threads = 16 waves = 4 waves/
// SIMD (R12 had 8 waves = 2/SIMD). R13 lesson: a wave issues in-order, so act
// and MFMA of the SAME wave serialize; overlap comes only from OTHER waves on
// the SIMD. 4 waves/SIMD doubles the tail-hiding capacity: per-SIMD MFMA pipe
// load is unchanged (64 x ~16cyc = ~1050) but each wave's serial tail
// (ds_read ~120 + act chain ~250) now interleaves 4-way under the pipe.
// Wave v owns units [16v,16v+16): tile q = rows q*256+16v+lm, 4 k-tiles ->
// 16 MFMA/wave/step; af = 64 dw/thread (fits the 128-reg/wave budget at
// 4 waves/EU). D-layout (R11/R12-validated): lane (ko,lm) reg j = row 4ko+j,
// cols equal -> lane holds all 4 gates of u = 16v+4ko+(lm&3); act in-register
// via 2-level static select on ru=lm&3; writers lm<4. Per-row scales, i8
// h-ring(16) + f16 ring flushed every 16 steps. Arithmetic identical to R12
// (absmax must repro 3.417e-3).
__global__ __attribute__((amdgpu_flat_work_group_size(1024, 1024),
                          amdgpu_waves_per_eu(4, 4)))
void lstm_main(const float* __restrict__ x, const float* __restrict__ Wih,
               const float* __restrict__ Whh, const float* __restrict__ bih,
               const float* __restrict__ bhh, float* __restrict__ out,
               unsigned* __restrict__ hist)   // hist f16x2 dwords: [b][step][128]
{
  __shared__ __align__(16) unsigned char qring[16 * 256];   // i8 h ring
  __shared__ __align__(16) unsigned      f16r[16 * 128];    // f16 h ring
  __shared__ float xs[SEQT];
  __shared__ float rowS[1024];                              // per-row gate scale

  const int t    = threadIdx.x;
  const int b    = blockIdx.x;
  const int v    = t >> 6;          // wave 0..15
  const int lane = t & 63;
  const int ko   = lane >> 4;       // k-16-group / D-row-quad 0..3
  const int lm   = lane & 15;       // A-row within tile / D-col
  const int ru   = lm & 3;          // reg this lane activates
  const int u    = 16 * v + 4 * ko + ru;   // unit (4 dup writers, lm<4 writes)

  ((float2*)xs)[t] = ((const float2*)(x + (size_t)b * SEQT))[t];
  if (t < 64) ((unsigned*)qring)[15 * 64 + t] = 0u;   // zero slot 15 (pre-step0)

  // ---- per-row max + quantize A-fragments (64 dw/thread) ----
  int32x4 af[4][4];
#pragma unroll
  for (int q = 0; q < 4; ++q) {
    const int row = q * 256 + 16 * v + lm;
    const float* rp = Whh + (size_t)row * HID + 16 * ko;
    float mx = 1e-20f;
#pragma unroll
    for (int kt = 0; kt < 4; ++kt) {
      const float4* p = (const float4*)(rp + 64 * kt);
      mx = fmaxf(mx, fmaxf(fmaxf(max4(p[0]), max4(p[1])),
                           fmaxf(max4(p[2]), max4(p[3]))));
    }
    mx = fmaxf(mx, __shfl_xor(mx, 16, 64));   // reduce across ko groups
    mx = fmaxf(mx, __shfl_xor(mx, 32, 64));
    const float winv = 127.f / mx;
    if (ko == 0) rowS[row] = mx * (1.f / (127.f * 127.f));
#pragma unroll
    for (int kt = 0; kt < 4; ++kt) {
      const float4* p = (const float4*)(rp + 64 * kt);
      int32x4 vv;
#pragma unroll
      for (int d = 0; d < 4; ++d) {
        float4 f = p[d];
        int q0 = (int)__builtin_rintf(f.x * winv);
        int q1 = (int)__builtin_rintf(f.y * winv);
        int q2 = (int)__builtin_rintf(f.z * winv);
        int q3 = (int)__builtin_rintf(f.w * winv);
        vv[d] = (q0 & 255) | ((q1 & 255) << 8) | ((q2 & 255) << 16) | ((q3 & 255) << 24);
      }
      af[q][kt] = vv;
    }
  }

  float biasu[4], wihu[4];
#pragma unroll
  for (int q = 0; q < 4; ++q) {
    int row = q * 256 + u;
    biasu[q] = bih[row] + bhh[row];
    wihu[q]  = Wih[row];
  }
  __syncthreads();
  float Su[4];
#pragma unroll
  for (int q = 0; q < 4; ++q) Su[q] = rowS[q * 256 + u];

  unsigned* histb = hist + (size_t)b * SEQT * 128;
  float c = 0.f, h = 0.f;
  const int32x4 z4 = {0, 0, 0, 0};

  for (int s = 0; s < SEQT; ++s) {
    float xv = xs[s];
    const unsigned char* qs = qring + ((s + 15) & 15) * 256;
    int32x4 bf[4];
#pragma unroll
    for (int kt = 0; kt < 4; ++kt)
      bf[kt] = *(const int32x4*)(qs + 64 * kt + 16 * ko);   // broadcast b128

    // 16 MFMA: 4 independent 4-deep chains
    int32x4 acc[4];
#pragma unroll
    for (int q = 0; q < 4; ++q)
      acc[q] = __builtin_amdgcn_mfma_i32_16x16x64_i8(af[q][0], bf[0], z4, 0, 0, 0);
#pragma unroll
    for (int kt = 1; kt < 4; ++kt)
#pragma unroll
      for (int q = 0; q < 4; ++q)
        acc[q] = __builtin_amdgcn_mfma_i32_16x16x64_i8(af[q][kt], bf[kt], acc[q], 0, 0, 0);

    // static select on ru: gate q of unit u = acc[q][ru]
    float aq[4];
#pragma unroll
    for (int q = 0; q < 4; ++q) {
      int32x4 vv = acc[q];
      int e01 = (ru & 1) ? vv[1] : vv[0];
      int e23 = (ru & 1) ? vv[3] : vv[2];
      int gv  = (ru & 2) ? e23 : e01;
      aq[q] = __builtin_fmaf((float)gv, Su[q],
                             __builtin_fmaf(wihu[q], xv, biasu[q]));
    }

    float I = sigf(aq[0]), F = sigf(aq[1]), G = tanhf_fast(aq[2]), O = sigf(aq[3]);
    c = F * c + I * G;
    h = O * tanhf_fast(c);

    if (lm < 4) {                                  // one writer per unit
      int qv = (int)__builtin_rintf(h * 127.f);
      ((char*)qring)[(s & 15) * 256 + u]    = (char)qv;       // next B-source
      ((_Float16*)f16r)[(s & 15) * 256 + u] = (_Float16)h;    // hist ring
    }
    __syncthreads();                               // h ring ready for step s+1

    if ((s & 15) == 15) {                          // flush 16 steps of h
      if (t < 512) {
        uint4 vv = *(const uint4*)(f16r + 4 * t);
        *(uint4*)(histb + (size_t)(s - 15) * 128 + 4 * t) = vv;
      }
      __syncthreads();                             // protect ring vs next writes
    }
  }

  if (lm < 4) {
    out[NB * SEQT + b * HID + u]            = h;   // h_n
    out[NB * SEQT + NB * HID + b * HID + u] = c;   // c_n
  }
}

// y[b,t] = Wfc . h[b,t,:] + bfc  — one wave per output, coalesced 8B/lane loads.
__global__ __launch_bounds__(256) void lstm_head(
    const unsigned* __restrict__ hist, const float* __restrict__ Wfc,
    const float* __restrict__ bfc, float* __restrict__ y)
{
  int gw   = (blockIdx.x * 256 + threadIdx.x) >> 6;  // global wave id = output idx
  int lane = threadIdx.x & 63;
  uint2 hv = ((const uint2*)(hist + (size_t)gw * 128))[lane];
  float4 w = ((const float4*)Wfc)[lane];
  h2 p0 = __builtin_bit_cast(h2, hv.x);
  h2 p1 = __builtin_bit_cast(h2, hv.y);
  float s = (float)p0.x * w.x + (float)p0.y * w.y +
            (float)p1.x * w.z + (float)p1.y * w.w;
#pragma unroll
  for (int m = 32; m; m >>= 1) s += __shfl_xor(s, m, 64);
  if (lane == 0) y[gw] = s + bfc[0];
}

extern "C" void kernel_launch(void* const* d_in, const int* in_sizes, int n_in,
                              void* d_out, int out_size, void* d_ws, size_t ws_size,
                              hipStream_t stream)
{
  const float* x   = (const float*)d_in[0];
  const float* Wih = (const float*)d_in[1];
  const float* Whh = (const float*)d_in[2];
  const float* bih = (const float*)d_in[3];
  const float* bhh = (const float*)d_in[4];
  const float* Wfc = (const float*)d_in[5];
  const float* bfc = (const float*)d_in[6];
  float* out      = (float*)d_out;
  unsigned* hist  = (unsigned*)d_ws;   // 64*2048*128 dwords = 64 MiB

  (void)in_sizes; (void)n_in; (void)out_size; (void)ws_size;

  lstm_main<<<dim3(NB), dim3(1024), 0, stream>>>(x, Wih, Whh, bih, bhh, out, hist);
  lstm_head<<<dim3((NB * SEQT) / 4), dim3(256), 0, stream>>>(hist, Wfc, bfc, out);
}

// Round 15
// 1685.764 us; speedup vs baseline: 1.7301x; 1.0557x over previous
//
#include <hip/hip_runtime.h>
#include <hip/hip_fp16.h>

#define SEQT 2048
#define HID  256
#define NB   64

typedef int int32x4 __attribute__((ext_vector_type(4)));
typedef _Float16 h2 __attribute__((ext_vector_type(2)));

#define LOG2E 1.4426950408889634f
static __device__ __forceinline__ float sigf(float x) {
  return __builtin_amdgcn_rcpf(1.f + __builtin_amdgcn_exp2f(-LOG2E * x));
}
static __device__ __forceinline__ float tanhf_fast(float x) {
  float e = __builtin_amdgcn_exp2f(-2.f * LOG2E * fabsf(x));
  float r = (1.f - e) * __builtin_amdgcn_rcpf(1.f + e);
  return copysignf(r, x);
}
static __device__ __forceinline__ float max4(float4 f) {
  return fmaxf(fmaxf(fabsf(f.x), fabsf(f.y)), fmaxf(fabsf(f.z), fabsf(f.w)));
}
// Workgroup barrier that waits ONLY lgkmcnt (LDS), never vmcnt: the 16-step
// hist-flush global stores drain lazily instead of stalling the next barrier
// (__syncthreads emits s_waitcnt vmcnt(0) lgkmcnt(0) before s_barrier).
// "memory" clobber gives IR-level ordering of the LDS accesses around it.
static __device__ __forceinline__ void barrier_lds_only() {
  asm volatile("s_waitcnt lgkmcnt(0)\n\ts_barrier" ::: "memory");
}

// One WG (512 thr = 8 waves) per batch. Gates = Whh*h via mfma_i32_16x16x64_i8
// (B = h broadcast to 16 cols). R12 structure (best so far, 1643us), R15 tail
// trims: lds-only barrier (no vmcnt drain), 32-slot f16 ring (no post-flush
// barrier), next-step act-base precomputed during MFMA phase, setprio(1)
// around the MFMA chain (T5: act/MFMA wave-role diversity). Wave w owns all 4
// gates of units [32w,32w+32): tile r=(q,sh) = rows q*256+32w+16sh (8 tiles x
// 4 k-tiles = 32 MFMA/wave/step = A-coverage floor). D-layout (HW-validated
// R11/R12): lane (ko,lm) reg j holds row 4ko+j of each tile, cols equal ->
// the SAME lane holds I,F,G,O of unit u = 32w+16su+4ko+ru. Activations
// in-register via static cndmask select tree; ONE barrier/step. Per-row
// weight scales. i8 h-ring (16 slots); f16 ring (32 slots) flushed every 16.
__global__ __attribute__((amdgpu_flat_work_group_size(512, 512),
                          amdgpu_waves_per_eu(2, 2)))
void lstm_main(const float* __restrict__ x, const float* __restrict__ Wih,
               const float* __restrict__ Whh, const float* __restrict__ bih,
               const float* __restrict__ bhh, float* __restrict__ out,
               unsigned* __restrict__ hist)   // hist f16x2 dwords: [b][step][128]
{
  __shared__ __align__(16) unsigned char qring[16 * 256];   // i8 h ring
  __shared__ __align__(16) unsigned      f16r[32 * 128];    // f16 h ring (32 slots)
  __shared__ float xs[SEQT];
  __shared__ float rowS[1024];                              // per-row gate scale

  const int t    = threadIdx.x;
  const int b    = blockIdx.x;
  const int w    = t >> 6;
  const int lane = t & 63;
  const int ko   = lane >> 4;       // k-16-group / D-row-quad 0..3
  const int lm   = lane & 15;       // A-row within tile / D-col
  const int su   = (lm >> 2) & 1;   // tile-half this lane activates
  const int ru   = lm & 3;          // reg this lane activates
  const int u    = 32 * w + 16 * su + 4 * ko + ru;   // unit (dup for lm>=8)

  ((float4*)xs)[t] = ((const float4*)(x + (size_t)b * SEQT))[t];
  if (t < 64) ((unsigned*)qring)[15 * 64 + t] = 0u;   // zero slot 15 (h pre-step0)

  // ---- per-row max + quantize A-fragments (128 dw/thread -> AGPR) ----
  int32x4 af[8][4];
#pragma unroll
  for (int r = 0; r < 8; ++r) {
    const int q = r >> 1, sh = r & 1;
    const int row = q * 256 + 32 * w + 16 * sh + lm;
    const float* rp = Whh + (size_t)row * HID + 16 * ko;
    float mx = 1e-20f;
#pragma unroll
    for (int kt = 0; kt < 4; ++kt) {
      const float4* p = (const float4*)(rp + 64 * kt);
      mx = fmaxf(mx, fmaxf(fmaxf(max4(p[0]), max4(p[1])),
                           fmaxf(max4(p[2]), max4(p[3]))));
    }
    mx = fmaxf(mx, __shfl_xor(mx, 16, 64));   // reduce across ko groups
    mx = fmaxf(mx, __shfl_xor(mx, 32, 64));
    const float winv = 127.f / mx;
    if (ko == 0) rowS[row] = mx * (1.f / (127.f * 127.f));
#pragma unroll
    for (int kt = 0; kt < 4; ++kt) {
      const float4* p = (const float4*)(rp + 64 * kt);
      int32x4 v;
#pragma unroll
      for (int d = 0; d < 4; ++d) {
        float4 f = p[d];
        int q0 = (int)__builtin_rintf(f.x * winv);
        int q1 = (int)__builtin_rintf(f.y * winv);
        int q2 = (int)__builtin_rintf(f.z * winv);
        int q3 = (int)__builtin_rintf(f.w * winv);
        v[d] = (q0 & 255) | ((q1 & 255) << 8) | ((q2 & 255) << 16) | ((q3 & 255) << 24);
      }
      af[r][kt] = v;
    }
  }

  float biasu[4], wihu[4];
#pragma unroll
  for (int q = 0; q < 4; ++q) {
    int row = q * 256 + u;
    biasu[q] = bih[row] + bhh[row];
    wihu[q]  = Wih[row];
  }
  __syncthreads();
  float Su[4];
#pragma unroll
  for (int q = 0; q < 4; ++q) Su[q] = rowS[q * 256 + u];

  unsigned* histb = hist + (size_t)b * SEQT * 128;
  float c = 0.f, h = 0.f;
  const int32x4 z4 = {0, 0, 0, 0};

  // act base for step 0 (x contribution + bias), updated one step ahead
  float basev[4];
#pragma unroll
  for (int q = 0; q < 4; ++q)
    basev[q] = __builtin_fmaf(wihu[q], xs[0], biasu[q]);

  for (int s = 0; s < SEQT; ++s) {
    const unsigned char* qs = qring + ((s + 15) & 15) * 256;
    int32x4 bf[4];
#pragma unroll
    for (int kt = 0; kt < 4; ++kt)
      bf[kt] = *(const int32x4*)(qs + 64 * kt + 16 * ko);   // broadcast b128

    // 32 MFMA: 8 independent 4-deep chains (matrix pipe prioritized)
    __builtin_amdgcn_s_setprio(1);
    int32x4 acc[8];
#pragma unroll
    for (int r = 0; r < 8; ++r)
      acc[r] = __builtin_amdgcn_mfma_i32_16x16x64_i8(af[r][0], bf[0], z4, 0, 0, 0);
#pragma unroll
    for (int kt = 1; kt < 4; ++kt)
#pragma unroll
      for (int r = 0; r < 8; ++r)
        acc[r] = __builtin_amdgcn_mfma_i32_16x16x64_i8(af[r][kt], bf[kt], acc[r], 0, 0, 0);
    __builtin_amdgcn_s_setprio(0);

    // next step's act base: issues while the MFMA chains drain
    float basen[4];
    {
      float xn = xs[(s + 1) & (SEQT - 1)];
#pragma unroll
      for (int q = 0; q < 4; ++q)
        basen[q] = __builtin_fmaf(wihu[q], xn, biasu[q]);
    }

    // static select: gate q of unit u = acc[2q+su][ru]; act in-register
    float aq[4];
#pragma unroll
    for (int q = 0; q < 4; ++q) {
      int32x4 v0 = acc[2 * q], v1 = acc[2 * q + 1];
      int e0 = su ? v1[0] : v0[0];
      int e1 = su ? v1[1] : v0[1];
      int e2 = su ? v1[2] : v0[2];
      int e3 = su ? v1[3] : v0[3];
      int g01 = (ru & 1) ? e1 : e0;
      int g23 = (ru & 1) ? e3 : e2;
      int gv  = (ru & 2) ? g23 : g01;
      aq[q] = __builtin_fmaf((float)gv, Su[q], basev[q]);
    }

    float I = sigf(aq[0]), F = sigf(aq[1]), G = tanhf_fast(aq[2]), O = sigf(aq[3]);
    c = F * c + I * G;
    h = O * tanhf_fast(c);

    if (lm < 8) {                                  // one writer per unit
      int qv = (int)__builtin_rintf(h * 127.f);
      ((char*)qring)[(s & 15) * 256 + u]    = (char)qv;       // next B-source
      ((_Float16*)f16r)[(s & 31) * 256 + u] = (_Float16)h;    // hist ring
    }
#pragma unroll
    for (int q = 0; q < 4; ++q) basev[q] = basen[q];

    barrier_lds_only();                            // h ring ready for step s+1

    if ((s & 15) == 15) {                          // flush 16 steps of h
      // slots (s-15..s)&31 are not rewritten for another 16 steps -> no
      // barrier needed after this block (32-slot ring).
      int g  = 4 * t;
      int sl = g >> 7, uu = g & 127;
      int step0 = s - 15;
      uint4 v = *(const uint4*)(f16r + (size_t)((step0 + sl) & 31) * 128 + uu);
      *(uint4*)(histb + (size_t)(step0 + sl) * 128 + uu) = v;
    }
  }

  if (lm < 8) {
    out[NB * SEQT + b * HID + u]            = h;   // h_n
    out[NB * SEQT + NB * HID + b * HID + u] = c;   // c_n
  }
}

// y[b,t] = Wfc . h[b,t,:] + bfc  — one wave per output, coalesced 8B/lane loads.
__global__ __launch_bounds__(256) void lstm_head(
    const unsigned* __restrict__ hist, const float* __restrict__ Wfc,
    const float* __restrict__ bfc, float* __restrict__ y)
{
  int gw   = (blockIdx.x * 256 + threadIdx.x) >> 6;  // global wave id = output idx
  int lane = threadIdx.x & 63;
  uint2 hv = ((const uint2*)(hist + (size_t)gw * 128))[lane];
  float4 w = ((const float4*)Wfc)[lane];
  h2 p0 = __builtin_bit_cast(h2, hv.x);
  h2 p1 = __builtin_bit_cast(h2, hv.y);
  float s = (float)p0.x * w.x + (float)p0.y * w.y +
            (float)p1.x * w.z + (float)p1.y * w.w;
#pragma unroll
  for (int m = 32; m; m >>= 1) s += __shfl_xor(s, m, 64);
  if (lane == 0) y[gw] = s + bfc[0];
}

extern "C" void kernel_launch(void* const* d_in, const int* in_sizes, int n_in,
                              void* d_out, int out_size, void* d_ws, size_t ws_size,
                              hipStream_t stream)
{
  const float* x   = (const float*)d_in[0];
  const float* Wih = (const float*)d_in[1];
  const float* Whh = (const float*)d_in[2];
  const float* bih = (const float*)d_in[3];
  const float* bhh = (const float*)d_in[4];
  const float* Wfc = (const float*)d_in[5];
  const float* bfc = (const float*)d_in[6];
  float* out      = (float*)d_out;
  unsigned* hist  = (unsigned*)d_ws;   // 64*2048*128 dwords = 64 MiB

  (void)in_sizes; (void)n_in; (void)out_size; (void)ws_size;

  lstm_main<<<dim3(NB), dim3(512), 0, stream>>>(x, Wih, Whh, bih, bhh, out, hist);
  lstm_head<<<dim3((NB * SEQT) / 4), dim3(256), 0, stream>>>(hist, Wfc, bfc, out);
}

// Round 16
// 1649.305 us; speedup vs baseline: 1.7683x; 1.0221x over previous
//
#include <hip/hip_runtime.h>
#include <hip/hip_fp16.h>

#define SEQT 2048
#define HID  256
#define NB   64

typedef int int32x4 __attribute__((ext_vector_type(4)));
typedef _Float16 h2 __attribute__((ext_vector_type(2)));

#define LOG2E 1.4426950408889634f
static __device__ __forceinline__ float tanhf_fast(float x) {
  float e = __builtin_amdgcn_exp2f(-2.f * LOG2E * fabsf(x));
  float r = (1.f - e) * __builtin_amdgcn_rcpf(1.f + e);
  return copysignf(r, x);
}
static __device__ __forceinline__ float max4(float4 f) {
  return fmaxf(fmaxf(fabsf(f.x), fabsf(f.y)), fmaxf(fabsf(f.z), fabsf(f.w)));
}
// DPP row_ror:8 — swap lane lm <-> lm+8 within each 16-lane row (pure VALU)
static __device__ __forceinline__ float ror8f(float v) {
  int p = __builtin_amdgcn_update_dpp(0, __builtin_bit_cast(int, v),
                                      0x128, 0xF, 0xF, true);
  return __builtin_bit_cast(float, p);
}

// One WG (512 thr = 8 waves) per batch. Gates = Whh*h via mfma_i32_16x16x64_i8
// (B = h broadcast to 16 cols). R12 structure (best, 1643us) + R16 change:
// the act phase is SPLIT across the redundant lane pair (lm, lm+8) — R12
// computed all 4 gates' activations twice (once per half). Now lo half (lm<8)
// computes gates I,G; hi half computes F,O, both via tanh-unified sigmoid
// (sig(x)=0.5*tanh(x/2)+0.5; per-lane affine consts -> no divergent branch).
// P=I*G and F' swap halves with one DPP row_ror:8; O' broadcasts with another.
// c is updated identically in all lanes (replica-consistent); h is valid on
// the writer half (lm<8). Transcendental chains 5->3, base/scale work halved.
// MFMA mapping identical to R12 (HW-validated): wave w owns all 4 gates of
// units [32w,32w+32); tile r=(q,sh) rows q*256+32w+16sh; gate q of unit
// u=32w+16su+4ko+ru = acc[2q+su][ru]. Per-row weight scales; i8 h-ring(16) +
// f16 ring flushed to hist every 16 steps.
__global__ __attribute__((amdgpu_flat_work_group_size(512, 512),
                          amdgpu_waves_per_eu(2, 2)))
void lstm_main(const float* __restrict__ x, const float* __restrict__ Wih,
               const float* __restrict__ Whh, const float* __restrict__ bih,
               const float* __restrict__ bhh, float* __restrict__ out,
               unsigned* __restrict__ hist)   // hist f16x2 dwords: [b][step][128]
{
  __shared__ __align__(16) unsigned char qring[16 * 256];   // i8 h ring
  __shared__ __align__(16) unsigned      f16r[16 * 128];    // f16 h ring
  __shared__ float xs[SEQT];
  __shared__ float rowS[1024];                              // per-row gate scale

  const int t    = threadIdx.x;
  const int b    = blockIdx.x;
  const int w    = t >> 6;
  const int lane = t & 63;
  const int ko   = lane >> 4;       // k-16-group / D-row-quad 0..3
  const int lm   = lane & 15;       // A-row within tile / D-col
  const int su   = (lm >> 2) & 1;   // tile-half this lane activates
  const int ru   = lm & 3;          // reg this lane activates
  const int su8  = (lm >> 3) & 1;   // redundant-pair half: 0=lo(I,G) 1=hi(F,O)
  const int u    = 32 * w + 16 * su + 4 * ko + ru;   // unit (pair lm/lm+8 dup)

  ((float4*)xs)[t] = ((const float4*)(x + (size_t)b * SEQT))[t];
  if (t < 64) ((unsigned*)qring)[15 * 64 + t] = 0u;   // zero slot 15 (h pre-step0)

  // ---- per-row max + quantize A-fragments (128 dw/thread -> AGPR) ----
  int32x4 af[8][4];
#pragma unroll
  for (int r = 0; r < 8; ++r) {
    const int q = r >> 1, sh = r & 1;
    const int row = q * 256 + 32 * w + 16 * sh + lm;
    const float* rp = Whh + (size_t)row * HID + 16 * ko;
    float mx = 1e-20f;
#pragma unroll
    for (int kt = 0; kt < 4; ++kt) {
      const float4* p = (const float4*)(rp + 64 * kt);
      mx = fmaxf(mx, fmaxf(fmaxf(max4(p[0]), max4(p[1])),
                           fmaxf(max4(p[2]), max4(p[3]))));
    }
    mx = fmaxf(mx, __shfl_xor(mx, 16, 64));   // reduce across ko groups
    mx = fmaxf(mx, __shfl_xor(mx, 32, 64));
    const float winv = 127.f / mx;
    if (ko == 0) rowS[row] = mx * (1.f / (127.f * 127.f));
#pragma unroll
    for (int kt = 0; kt < 4; ++kt) {
      const float4* p = (const float4*)(rp + 64 * kt);
      int32x4 v;
#pragma unroll
      for (int d = 0; d < 4; ++d) {
        float4 f = p[d];
        int q0 = (int)__builtin_rintf(f.x * winv);
        int q1 = (int)__builtin_rintf(f.y * winv);
        int q2 = (int)__builtin_rintf(f.z * winv);
        int q3 = (int)__builtin_rintf(f.w * winv);
        v[d] = (q0 & 255) | ((q1 & 255) << 8) | ((q2 & 255) << 16) | ((q3 & 255) << 24);
      }
      af[r][kt] = v;
    }
  }

  // per-lane constants for THIS HALF's two gates: slotA q=su8 (I/F),
  // slotB q=2+su8 (G/O)
  const int qA = su8, qB = 2 + su8;
  const float biasA = bih[qA * 256 + u] + bhh[qA * 256 + u];
  const float wihA  = Wih[qA * 256 + u];
  const float biasB = bih[qB * 256 + u] + bhh[qB * 256 + u];
  const float wihB  = Wih[qB * 256 + u];
  // slotA is always sigmoid-form; slotB: lo=tanh-form, hi=sigmoid-form
  const float scB = su8 ? 0.5f : 1.0f;
  const float amB = su8 ? 0.5f : 1.0f;
  const float abB = su8 ? 0.5f : 0.0f;
  __syncthreads();
  const float SuA = rowS[qA * 256 + u];
  const float SuB = rowS[qB * 256 + u];

  unsigned* histb = hist + (size_t)b * SEQT * 128;
  float c = 0.f, h = 0.f;
  const int32x4 z4 = {0, 0, 0, 0};

  for (int s = 0; s < SEQT; ++s) {
    float xv = xs[s];
    const unsigned char* qs = qring + ((s + 15) & 15) * 256;
    int32x4 bf[4];
#pragma unroll
    for (int kt = 0; kt < 4; ++kt)
      bf[kt] = *(const int32x4*)(qs + 64 * kt + 16 * ko);   // broadcast b128

    // 32 MFMA: 8 independent 4-deep chains
    int32x4 acc[8];
#pragma unroll
    for (int r = 0; r < 8; ++r)
      acc[r] = __builtin_amdgcn_mfma_i32_16x16x64_i8(af[r][0], bf[0], z4, 0, 0, 0);
#pragma unroll
    for (int kt = 1; kt < 4; ++kt)
#pragma unroll
      for (int r = 0; r < 8; ++r)
        acc[r] = __builtin_amdgcn_mfma_i32_16x16x64_i8(af[r][kt], bf[kt], acc[r], 0, 0, 0);

    // ---- split act: this half's 2 gates only ----
    // slot A: tile acc[2*su8+su], elem ru  (lo: I, hi: F)
    float aA, aB;
    {
      int e0 = su8 ? (su ? acc[3][0] : acc[2][0]) : (su ? acc[1][0] : acc[0][0]);
      int e1 = su8 ? (su ? acc[3][1] : acc[2][1]) : (su ? acc[1][1] : acc[0][1]);
      int e2 = su8 ? (su ? acc[3][2] : acc[2][2]) : (su ? acc[1][2] : acc[0][2]);
      int e3 = su8 ? (su ? acc[3][3] : acc[2][3]) : (su ? acc[1][3] : acc[0][3]);
      int g01 = (ru & 1) ? e1 : e0;
      int g23 = (ru & 1) ? e3 : e2;
      int gv  = (ru & 2) ? g23 : g01;
      aA = __builtin_fmaf((float)gv, SuA, __builtin_fmaf(wihA, xv, biasA));
    }
    // slot B: tile acc[4+2*su8+su], elem ru  (lo: G, hi: O)
    {
      int e0 = su8 ? (su ? acc[7][0] : acc[6][0]) : (su ? acc[5][0] : acc[4][0]);
      int e1 = su8 ? (su ? acc[7][1] : acc[6][1]) : (su ? acc[5][1] : acc[4][1]);
      int e2 = su8 ? (su ? acc[7][2] : acc[6][2]) : (su ? acc[5][2] : acc[4][2]);
      int e3 = su8 ? (su ? acc[7][3] : acc[6][3]) : (su ? acc[5][3] : acc[4][3]);
      int g01 = (ru & 1) ? e1 : e0;
      int g23 = (ru & 1) ? e3 : e2;
      int gv  = (ru & 2) ? g23 : g01;
      aB = __builtin_fmaf((float)gv, SuB, __builtin_fmaf(wihB, xv, biasB));
    }

    float gA = __builtin_fmaf(tanhf_fast(aA * 0.5f), 0.5f, 0.5f); // I' or F'
    float gB = __builtin_fmaf(tanhf_fast(aB * scB), amB, abB);    // G' or O'

    float own = gA * (su8 ? 1.0f : gB);      // lo: P=I'*G'   hi: F'
    float oth = ror8f(own);                  // lo: F'        hi: P
    float Fv  = su8 ? own : oth;
    float Pv  = su8 ? oth : own;
    c = __builtin_fmaf(Fv, c, Pv);           // identical in both halves
    float th = tanhf_fast(c);
    float Ox = ror8f(gB);                    // lo: O'        hi: G' (unused)
    h = Ox * th;                             // valid on lo half

    if (lm < 8) {                            // one writer per unit
      int qv = (int)__builtin_rintf(h * 127.f);
      ((char*)qring)[(s & 15) * 256 + u]    = (char)qv;       // next B-source
      ((_Float16*)f16r)[(s & 15) * 256 + u] = (_Float16)h;    // hist ring
    }
    __syncthreads();                         // h ring ready for step s+1

    if ((s & 15) == 15) {                    // flush 16 steps of h
      uint4 v = *(const uint4*)(f16r + 4 * t);
      *(uint4*)(histb + (size_t)(s - 15) * 128 + 4 * t) = v;
      __syncthreads();                       // protect ring vs next writes
    }
  }

  if (lm < 8) {
    out[NB * SEQT + b * HID + u]            = h;   // h_n
    out[NB * SEQT + NB * HID + b * HID + u] = c;   // c_n
  }
}

// y[b,t] = Wfc . h[b,t,:] + bfc  — one wave per output, coalesced 8B/lane loads.
__global__ __launch_bounds__(256) void lstm_head(
    const unsigned* __restrict__ hist, const float* __restrict__ Wfc,
    const float* __restrict__ bfc, float* __restrict__ y)
{
  int gw   = (blockIdx.x * 256 + threadIdx.x) >> 6;  // global wave id = output idx
  int lane = threadIdx.x & 63;
  uint2 hv = ((const uint2*)(hist + (size_t)gw * 128))[lane];
  float4 w = ((const float4*)Wfc)[lane];
  h2 p0 = __builtin_bit_cast(h2, hv.x);
  h2 p1 = __builtin_bit_cast(h2, hv.y);
  float s = (float)p0.x * w.x + (float)p0.y * w.y +
            (float)p1.x * w.z + (float)p1.y * w.w;
#pragma unroll
  for (int m = 32; m; m >>= 1) s += __shfl_xor(s, m, 64);
  if (lane == 0) y[gw] = s + bfc[0];
}

extern "C" void kernel_launch(void* const* d_in, const int* in_sizes, int n_in,
                              void* d_out, int out_size, void* d_ws, size_t ws_size,
                              hipStream_t stream)
{
  const float* x   = (const float*)d_in[0];
  const float* Wih = (const float*)d_in[1];
  const float* Whh = (const float*)d_in[2];
  const float* bih = (const float*)d_in[3];
  const float* bhh = (const float*)d_in[4];
  const float* Wfc = (const float*)d_in[5];
  const float* bfc = (const float*)d_in[6];
  float* out      = (float*)d_out;
  unsigned* hist  = (unsigned*)d_ws;   // 64*2048*128 dwords = 64 MiB

  (void)in_sizes; (void)n_in; (void)out_size; (void)ws_size;

  lstm_main<<<dim3(NB), dim3(512), 0, stream>>>(x, Wih, Whh, bih, bhh, out, hist);
  lstm_head<<<dim3((NB * SEQT) / 4), dim3(256), 0, stream>>>(hist, Wfc, bfc, out);
}